// Round 5
// baseline (349.187 us; speedup 1.0000x reference)
//
#include <hip/hip_runtime.h>
#include <hip/hip_bf16.h>
#include <stdint.h>

using short8 = __attribute__((ext_vector_type(8))) short;
using f32x4  = __attribute__((ext_vector_type(4))) float;

#define NBITS 3
#define NHEADS 8
#define BATCH 8192
#define DFEAT 512
#define DBASE 1024
#define DHH   1024
#define DOUT  512
#define XCOLS (NBITS + DFEAT)   // 515

static __device__ __forceinline__ unsigned short f2bf(float f) {
    union { float f; unsigned u; } v; v.f = f;
    unsigned r = v.u + 0x7FFFu + ((v.u >> 16) & 1u);   // RNE
    return (unsigned short)(r >> 16);
}

// ---------------- bucket rows by head ----------------
__global__ void k_bucket(const float* __restrict__ x, int* __restrict__ cnt,
                         int* __restrict__ rows) {
    int r = blockIdx.x * 256 + threadIdx.x;
    if (r >= BATCH) return;
    const float* xr = x + (size_t)r * XCOLS;
    int h = (xr[0] > 0.5f ? 1 : 0) | (xr[1] > 0.5f ? 2 : 0) | (xr[2] > 0.5f ? 4 : 0);
    int slot = atomicAdd(cnt + h, 1);
    rows[h * BATCH + slot] = r;
}

// ---------------- feat fp32 -> bf16 [8192][512] ----------------
__global__ void k_feat(const float* __restrict__ x, unsigned short* __restrict__ feat) {
    int t = blockIdx.x * 256 + threadIdx.x;
    int row = t >> 6, c8 = (t & 63) << 3;
    const float* src = x + (size_t)row * XCOLS + NBITS + c8;
    short8 v;
#pragma unroll
    for (int i = 0; i < 8; ++i) v[i] = (short)f2bf(src[i]);
    *(short8*)(feat + (size_t)row * DFEAT + c8) = v;
}

// ---------------- W[b][K][N] fp32 -> WT[b][N][K] bf16 ----------------
__global__ void k_transpose(const float* __restrict__ W, unsigned short* __restrict__ WT,
                            int K, int N) {
    __shared__ float tile[32][33];
    int b  = blockIdx.z;
    int n0 = blockIdx.x << 5, k0 = blockIdx.y << 5;
    int tx = threadIdx.x & 31, ty = threadIdx.x >> 5;
    const float* Wb = W + (size_t)b * K * N;
    unsigned short* WTb = WT + (size_t)b * K * N;
#pragma unroll
    for (int j = 0; j < 32; j += 8)
        tile[ty + j][tx] = Wb[(size_t)(k0 + ty + j) * N + n0 + tx];
    __syncthreads();
#pragma unroll
    for (int j = 0; j < 32; j += 8)
        WTb[(size_t)(n0 + ty + j) * K + k0 + tx] = f2bf(tile[tx][ty + j]);
}

// ============ 128xBN MFMA GEMM, 8 waves, BK=64, TRIPLE-buffered LDS, counted vmcnt ============
// C[rows][n] = act(A[rows] @ BT[head]^T + bias[head]);  BT is [N][K] row-major.
// NF = n-frags per wave: 4 -> BN=256, 2 -> BN=128.
// Pipeline: stage tile kt+2 each step; raw s_barrier; s_waitcnt vmcnt(2*steps-in-flight)
// (NEVER 0 in the loop) so prefetch loads survive barriers (T4).
// Chunk swizzle: 16B chunk at (row r, phys p) holds logical kchunk p^(r&7) (involution,
// applied on the global source AND the ds_read address; LDS dest stays linear).
template<bool GATHER, bool RELU, bool OUTBF16, int NF>
__global__ __launch_bounds__(512, 1)
void k_gemm3(const unsigned short* __restrict__ A, int lda, int K,
             const unsigned short* __restrict__ BT,
             const float* __restrict__ bias,
             void* __restrict__ C, int ldc,
             const int* __restrict__ rowsAll, const int* __restrict__ cntAll,
             int Nfull, int nshift) {
    constexpr int BN  = NF * 64;         // 256 or 128
    constexpr int BNB = BN * 128;        // B bytes per buf: 32768 / 16384
    constexpr int NB  = BNB / 8192;      // B stage instrs per thread: 4 / 2

    const int bid  = blockIdx.x;
    const int mt   = bid & 63;
    const int nt   = (bid >> 6) & ((1 << nshift) - 1);
    const int head = GATHER ? (bid >> (6 + nshift)) : 0;
    const int m0 = mt * 128;
    const int n0 = nt * BN;
    int M = BATCH;
    const int* rows = nullptr;
    if (GATHER) {
        M = cntAll[head];
        if (m0 >= M) return;             // uniform early exit (before any barrier)
        rows = rowsAll + head * BATCH;
    }
    const unsigned short* BTh = BT + (size_t)head * Nfull * K;
    const float* biash = bias + (size_t)head * Nfull;

    __shared__ __align__(16) char lds[3 * 16384 + 3 * BNB];
    char* ldsA = lds;                    // 3 bufs x 16 KB
    char* ldsB = lds + 3 * 16384;        // 3 bufs x BNB

    const int t    = threadIdx.x;
    const int w    = t >> 6;
    const int lane = t & 63;
    const int wr = w >> 2, wc = w & 3;   // 2 (M) x 4 (N) waves
    const int ln = lane & 15, lq = lane >> 4;

    // ---- staging source pointers (swizzle pre-applied to global k-chunk) ----
    const unsigned short* gA[2];
    {
        int rl  = t >> 3;                // 0..63 row within half
        int kch = (t & 7) ^ (rl & 7);
#pragma unroll
        for (int h = 0; h < 2; ++h) {
            int idx = m0 + h * 64 + rl;
            int r;
            if (GATHER) { idx = idx < M ? idx : (M - 1); r = rows[idx]; }
            else r = idx;
            gA[h] = A + (size_t)r * lda + kch * 8;
        }
    }
    const unsigned short* gB[NB];
#pragma unroll
    for (int i = 0; i < NB; ++i) {
        int c   = i * 512 + t;
        int cl  = c >> 3;                // col 0..BN-1
        int kch = (c & 7) ^ (cl & 7);
        gB[i] = BTh + (size_t)(n0 + cl) * K + kch * 8;
    }

#define STAGE(kt_, d_)                                                                     \
    { _Pragma("unroll") for (int h = 0; h < 2; ++h)                                        \
        __builtin_amdgcn_global_load_lds(                                                  \
            (const __attribute__((address_space(1))) void*)(gA[h] + (kt_) * 64),           \
            (__attribute__((address_space(3))) void*)(ldsA + (d_) * 16384 + h * 8192 + w * 1024), \
            16, 0, 0);                                                                     \
      _Pragma("unroll") for (int i = 0; i < NB; ++i)                                       \
        __builtin_amdgcn_global_load_lds(                                                  \
            (const __attribute__((address_space(1))) void*)(gB[i] + (kt_) * 64),           \
            (__attribute__((address_space(3))) void*)(ldsB + (d_) * BNB + i * 8192 + w * 1024), \
            16, 0, 0); }

    // counted waits: per wave per step loads = 2 + NB; keep 2 steps in flight.
#define WAITV_STEADY()                                                                     \
    { if constexpr (NF == 4) asm volatile("s_waitcnt vmcnt(12)" ::: "memory");             \
      else                   asm volatile("s_waitcnt vmcnt(8)"  ::: "memory"); }

    f32x4 acc[4][NF] = {};
    const int NT = K >> 6;

    // prologue: stage tiles 0,1 into bufs 0,1
    STAGE(0, 0);
    STAGE(1, 1);

    for (int kt = 0; kt < NT; ++kt) {
        const int bc = kt % 3;                              // compute buf
        const int bs = (kt + 2) % 3;                        // stage buf
        const int ks = (kt + 2 < NT) ? kt + 2 : NT - 1;     // clamp (dangling loads are benign)
        STAGE(ks, bs);
        WAITV_STEADY();                                     // tile kt's DMA (this wave) landed
        __builtin_amdgcn_s_barrier();                       // tile kt ready block-wide
        const char* cA = ldsA + bc * 16384;
        const char* cB = ldsB + bc * BNB;
#pragma unroll
        for (int ksl = 0; ksl < 2; ++ksl) {
            short8 af[4], bf[NF];
#pragma unroll
            for (int m = 0; m < 4; ++m) {
                int rA = wr * 64 + m * 16 + ln;
                int ch = ((ksl << 2) | lq) ^ (ln & 7);
                af[m] = *(const short8*)(cA + rA * 128 + ch * 16);
            }
#pragma unroll
            for (int n = 0; n < NF; ++n) {
                int cBc = wc * (NF * 16) + n * 16 + ln;
                int ch  = ((ksl << 2) | lq) ^ (ln & 7);
                bf[n] = *(const short8*)(cB + cBc * 128 + ch * 16);
            }
            __builtin_amdgcn_s_setprio(1);
#pragma unroll
            for (int m = 0; m < 4; ++m)
#pragma unroll
                for (int n = 0; n < NF; ++n)
                    acc[m][n] = __builtin_amdgcn_mfma_f32_16x16x32_bf16(af[m], bf[n], acc[m][n], 0, 0, 0);
            __builtin_amdgcn_s_setprio(0);
        }
        __builtin_amdgcn_s_barrier();                       // readers done -> buf reusable
    }
#undef STAGE
#undef WAITV_STEADY

    // epilogue: C/D layout col = lane&15, row = (lane>>4)*4 + j
#pragma unroll
    for (int n = 0; n < NF; ++n) {
        int col = n0 + wc * (NF * 16) + n * 16 + ln;
        float bv = biash[col];
#pragma unroll
        for (int m = 0; m < 4; ++m) {
#pragma unroll
            for (int j = 0; j < 4; ++j) {
                int rt = wr * 64 + m * 16 + lq * 4 + j;
                int grow;
                if (GATHER) {
                    if (m0 + rt >= M) continue;
                    grow = rows[m0 + rt];
                } else {
                    grow = m0 + rt;
                }
                float v = acc[m][n][j] + bv;
                if (RELU) v = fmaxf(v, 0.0f);
                if (OUTBF16)
                    ((unsigned short*)C)[(size_t)grow * ldc + col] = f2bf(v);
                else
                    ((float*)C)[(size_t)grow * ldc + col] = v;
            }
        }
    }
}

extern "C" void kernel_launch(void* const* d_in, const int* in_sizes, int n_in,
                              void* d_out, int out_size, void* d_ws, size_t ws_size,
                              hipStream_t stream) {
    const float* x   = (const float*)d_in[0];
    const float* Wb  = (const float*)d_in[1];
    const float* bb  = (const float*)d_in[2];
    const float* Wh1 = (const float*)d_in[3];
    const float* bh1 = (const float*)d_in[4];
    const float* Wh2 = (const float*)d_in[5];
    const float* bh2 = (const float*)d_in[6];

    char* ws = (char*)d_ws;
    unsigned short* feat = (unsigned short*)(ws);                          //  8 MB
    unsigned short* WbT  = (unsigned short*)(ws + (8ull  << 20));          //  1 MB
    unsigned short* Wh1T = (unsigned short*)(ws + (9ull  << 20));          // 16 MB
    unsigned short* Wh2T = (unsigned short*)(ws + (25ull << 20));          //  8 MB
    unsigned short* base = (unsigned short*)(ws + (33ull << 20));          // 16 MB
    unsigned short* hbuf = (unsigned short*)(ws + (49ull << 20));          // 16 MB
    int* rows            = (int*)(ws + (65ull << 20));                     // 256 KB
    int* cnt             = (int*)(ws + (65ull << 20) + (256ull << 10));    // 32 B

    hipMemsetAsync(cnt, 0, NHEADS * sizeof(int), stream);
    k_bucket<<<BATCH / 256, 256, 0, stream>>>(x, cnt, rows);
    k_feat<<<(BATCH * 64) / 256, 256, 0, stream>>>(x, feat);
    k_transpose<<<dim3(DBASE / 32, DFEAT / 32, 1), 256, 0, stream>>>(Wb, WbT, DFEAT, DBASE);
    k_transpose<<<dim3(DHH / 32, DBASE / 32, NHEADS), 256, 0, stream>>>(Wh1, Wh1T, DBASE, DHH);
    k_transpose<<<dim3(DOUT / 32, DHH / 32, NHEADS), 256, 0, stream>>>(Wh2, Wh2T, DHH, DOUT);

    // GEMM1: base = relu(feat @ Wb + bb)   M=8192 K=512 N=1024 ; 64 mt x 4 nt (BN=256)
    k_gemm3<false, true, true, 4><<<256, 512, 0, stream>>>(
        feat, DFEAT, DFEAT, WbT, bb, base, DBASE, nullptr, nullptr, DBASE, 2);
    // GEMM2: h = relu(base @ Wh1[h] + bh1[h])  grouped, K=1024 N=1024 ; 64 mt x 4 nt x 8 heads
    k_gemm3<true, true, true, 4><<<2048, 512, 0, stream>>>(
        base, DBASE, DBASE, Wh1T, bh1, hbuf, DHH, rows, cnt, DHH, 2);
    // GEMM3: out = h @ Wh2[h] + bh2[h]  grouped, K=1024 N=512, fp32 out ; BN=128: 64 mt x 4 nt x 8 heads
    k_gemm3<true, false, false, 2><<<2048, 512, 0, stream>>>(
        hbuf, DHH, DHH, Wh2T, bh2, d_out, DOUT, rows, cnt, DOUT, 2);
}